// Round 9
// baseline (312.956 us; speedup 1.0000x reference)
//
#include <hip/hip_runtime.h>
#include <hip/hip_fp16.h>

// MultiHeadAttention: n=4096, e=128, H=8, fp32 in/out.
// [conv_weights] w_proj -> f16^T; w_qkv -> f16 permuted-transposed (Q pre-scaled
//                by log2(e) so flash softmax runs in exp2 units)
// [qkv_gemm2]    f16 MFMA GEMM; V stored d-major, Q/K n-major via LDS transpose
// [flash_attn]   512-thr (8 waves), split-K x4, grid 512 = 2 blocks/CU (32 KB LDS
//                single-buffered K+V so two blocks co-reside -> 4 waves/SIMD).
//                Swapped QK^T, lane-local softmax, defer-max shfl-free common path,
//                in-lane P repack, PV. Cross-block TLP hides the stage wait.
// [proj_combine] fused 4-way split-K combine (exp2-scale stats) + proj GEMM

#define N_TOK 4096
#define DH 128
#define NH 8

#define EXP2F(x) __builtin_amdgcn_exp2f(x)

typedef _Float16 f16;
typedef __attribute__((ext_vector_type(8))) _Float16 f16x8;
typedef __attribute__((ext_vector_type(2))) __fp16 hf2;
typedef __attribute__((ext_vector_type(4))) float f32x4;

#define GLD16(gsrc, ldst) __builtin_amdgcn_global_load_lds( \
    (const __attribute__((address_space(1))) void*)(gsrc), \
    (__attribute__((address_space(3))) void*)(ldst), 16, 0, 0)

// ---------------- conv: both weight matrices, one launch ------------------
__global__ __launch_bounds__(256) void conv_weights(
    const float* __restrict__ w_proj, const float* __restrict__ w_qkv,
    const float* __restrict__ b_qkv,
    f16* __restrict__ wpT, f16* __restrict__ wqkvT, float* __restrict__ bperm)
{
  int t = blockIdx.x * 256 + threadIdx.x;   // 0 .. 524287
  if (t < 131072) {
    int k = t >> 7, col = t & 127;
    wpT[col * 1024 + k] = (f16)w_proj[t];
  } else {
    t -= 131072;                            // 0 .. 393215 = 128 * 3072
    int k = t / 3072;
    int col = t - k * 3072;
    int hh = col / 384;
    int rem = col - hh * 384;
    int d = rem / 3;
    int s = rem - d * 3;
    int colp = s * 1024 + hh * 128 + d;
    float scale = (s == 0) ? 1.4426950408889634f : 1.0f;
    wqkvT[colp * 128 + k] = (f16)(w_qkv[t] * scale);
    if (k == 0) bperm[colp] = b_qkv[col] * scale;
  }
}

// ---------------- qkv GEMM v2: f16 MFMA --------------------------------
__global__ __launch_bounds__(256) void qkv_gemm2(
    const float* __restrict__ x, const f16* __restrict__ wqkvT,
    const float* __restrict__ bperm,
    f16* __restrict__ Qh, f16* __restrict__ Kh, f16* __restrict__ Vt)
{
  const int cb = blockIdx.x;               // 0..23: s = cb>>3, h = cb&7
  const int rb = blockIdx.y;               // 0..31: rows rb*128
  const int tid = threadIdx.x;
  const int w = tid >> 6, lane = tid & 63;
  const int l16 = lane & 15, lhi = lane >> 4;
  const int s = cb >> 3, h = cb & 7;

  f16x8 xf[2][4];
#pragma unroll
  for (int m = 0; m < 2; ++m)
#pragma unroll
    for (int kt = 0; kt < 4; ++kt) {
      const float* xp = x + (size_t)(rb * 128 + w * 32 + m * 16 + l16) * 128 + kt * 32 + lhi * 8;
      f32x4 x0 = *(const f32x4*)xp, x1 = *(const f32x4*)(xp + 4);
      f16x8 v;
#pragma unroll
      for (int j = 0; j < 4; ++j) { v[j] = (f16)x0[j]; v[4 + j] = (f16)x1[j]; }
      xf[m][kt] = v;
    }

  f32x4 acc[8][2];
#pragma unroll
  for (int nt = 0; nt < 8; ++nt)
#pragma unroll
    for (int m = 0; m < 2; ++m) acc[nt][m] = (f32x4){0.f, 0.f, 0.f, 0.f};

#pragma unroll
  for (int nt = 0; nt < 8; ++nt)
#pragma unroll
    for (int kt = 0; kt < 4; ++kt) {
      f16x8 wf = *(const f16x8*)(wqkvT + (size_t)(cb * 128 + nt * 16 + l16) * 128 + kt * 32 + lhi * 8);
      acc[nt][0] = __builtin_amdgcn_mfma_f32_16x16x32_f16(wf, xf[0][kt], acc[nt][0], 0, 0, 0);
      acc[nt][1] = __builtin_amdgcn_mfma_f32_16x16x32_f16(wf, xf[1][kt], acc[nt][1], 0, 0, 0);
    }

#pragma unroll
  for (int nt = 0; nt < 8; ++nt) {
    f32x4 bb = *(const f32x4*)(bperm + cb * 128 + nt * 16 + 4 * lhi);
#pragma unroll
    for (int m = 0; m < 2; ++m) acc[nt][m] += bb;
  }

  if (s == 2) {            // V: direct d-major store [h*128+d][n]
#pragma unroll
    for (int nt = 0; nt < 8; ++nt)
#pragma unroll
      for (int m = 0; m < 2; ++m)
#pragma unroll
        for (int r = 0; r < 4; ++r)
          Vt[(size_t)(h * 128 + nt * 16 + 4 * lhi + r) * N_TOK + rb * 128 + w * 32 + m * 16 + l16] =
              (f16)acc[nt][m][r];
  } else {                 // Q/K: LDS transpose -> n-major [n][d]
    __shared__ f16 tr[128][136];
#pragma unroll
    for (int nt = 0; nt < 8; ++nt)
#pragma unroll
      for (int m = 0; m < 2; ++m)
#pragma unroll
        for (int r = 0; r < 4; ++r)
          tr[w * 32 + m * 16 + l16][nt * 16 + 4 * lhi + r] = (f16)acc[nt][m][r];
    __syncthreads();
    f16* dst = (s == 0 ? Qh : Kh) + (size_t)(h * N_TOK + rb * 128) * 128;
    int r = tid >> 1, dh = (tid & 1) * 64;
#pragma unroll
    for (int i = 0; i < 8; ++i)
      *(f16x8*)(dst + r * 128 + dh + i * 8) = *(const f16x8*)(&tr[r][dh + i * 8]);
  }
}

// ---------------- flash attention: 8 waves, split-K x4, 32 KB LDS --------
// grid 512: h = bid&7 (XCD pin), sp = (bid>>3)&3, qb = bid>>5 (0..15).
// Single-buffered K (16K) + V (16K); 2 blocks/CU -> cross-block TLP.
__global__ __launch_bounds__(512, 4) void flash_attn(
    const f16* __restrict__ Qh, const f16* __restrict__ Kh,
    const f16* __restrict__ Vt, f16* __restrict__ opart, float* __restrict__ mlpart)
{
  const int bid = blockIdx.x;
  const int h = bid & 7, sp = (bid >> 3) & 3, qb = bid >> 5;
  const int tid = threadIdx.x;
  const int w = tid >> 6, lane = tid & 63;
  const int l16 = lane & 15, lhi = lane >> 4;

  __shared__ __align__(16) char smem[32768];   // K @0 (16K), V @16K

  f16x8 qf[2][4];
#pragma unroll
  for (int m = 0; m < 2; ++m)
#pragma unroll
    for (int kt = 0; kt < 4; ++kt)
      qf[m][kt] = *(const f16x8*)(Qh +
          (size_t)(h * N_TOK + qb * 256 + w * 32 + m * 16 + l16) * DH + kt * 32 + lhi * 8);

  // K A-row permutation pi = 32*(nt>>1) + 8*(i>>2) + 4*(nt&1) + (i&3); XOR swizzle
  int koff[4][4], voff[2][8];
#pragma unroll
  for (int nt = 0; nt < 4; ++nt) {
    int row = 32 * (nt >> 1) + 8 * (l16 >> 2) + 4 * (nt & 1) + (l16 & 3);
    int fk = (row & 3) | ((row & 8) >> 1);
#pragma unroll
    for (int kt = 0; kt < 4; ++kt)
      koff[nt][kt] = row * 256 + ((kt * 4 + lhi) ^ fk) * 16;
  }
#pragma unroll
  for (int ks = 0; ks < 2; ++ks)
#pragma unroll
    for (int dt = 0; dt < 8; ++dt) {
      int rowv = dt * 16 + l16;
      voff[ks][dt] = rowv * 128 + (((ks * 4 + lhi) ^ (rowv & 7))) * 16;
    }

  f32x4 o[2][8];
#pragma unroll
  for (int m = 0; m < 2; ++m)
#pragma unroll
    for (int dt = 0; dt < 8; ++dt) o[m][dt] = (f32x4){0.f, 0.f, 0.f, 0.f};
  float mrun[2] = {-3e38f, -3e38f}, lrun[2] = {0.f, 0.f};   // lrun: per-lane partial

  const f16* Kgh = Kh + (size_t)h * N_TOK * DH;
  const f16* Vgh = Vt + (size_t)h * DH * N_TOK;

  // wave w stages 4 x GLD16 (K chunks 2w,2w+1 + V chunks 2w,2w+1), disjoint per wave
  auto stage = [&](int kb) {
    char* kd = smem;
    char* vd = smem + 16384;
#pragma unroll
    for (int c2 = 0; c2 < 2; ++c2) {
      int c = w * 2 + c2;   // 0..15
      {
        int row = c * 4 + (lane >> 4);
        int fk = (row & 3) | ((row & 8) >> 1);
        const f16* src = Kgh + (size_t)(kb * 64 + row) * DH + ((lane & 15) ^ fk) * 8;
        GLD16(src, kd + c * 1024);
      }
      {
        int row = c * 8 + (lane >> 3);
        const f16* src = Vgh + (size_t)row * N_TOK + kb * 64 + ((lane & 7) ^ (row & 7)) * 8;
        GLD16(src, vd + c * 1024);
      }
    }
  };

  const int kb0 = sp * 16;
  const char* kd = smem;
  const char* vd = smem + 16384;

  for (int it = 0; it < 16; ++it) {
    stage(kb0 + it);
    __syncthreads();               // stage writes landed (vmcnt(0) + barrier)

    f32x4 sv[2][4];
    __builtin_amdgcn_s_setprio(1);
#pragma unroll
    for (int nt = 0; nt < 4; ++nt) {
      f32x4 a0 = {0.f, 0.f, 0.f, 0.f}, a1 = {0.f, 0.f, 0.f, 0.f};
#pragma unroll
      for (int kt = 0; kt < 4; ++kt) {
        f16x8 kf = *(const f16x8*)(kd + koff[nt][kt]);
        a0 = __builtin_amdgcn_mfma_f32_16x16x32_f16(kf, qf[0][kt], a0, 0, 0, 0);
        a1 = __builtin_amdgcn_mfma_f32_16x16x32_f16(kf, qf[1][kt], a1, 0, 0, 0);
      }
      sv[0][nt] = a0; sv[1][nt] = a1;
    }
    __builtin_amdgcn_s_setprio(0);

    f16x8 pf[2][2];
#pragma unroll
    for (int m = 0; m < 2; ++m) {
      f32x4 mv;
#pragma unroll
      for (int r = 0; r < 4; ++r)
        mv[r] = fmaxf(fmaxf(sv[m][0][r], sv[m][1][r]), fmaxf(sv[m][2][r], sv[m][3][r]));
      float pmax = fmaxf(fmaxf(mv[0], mv[1]), fmaxf(mv[2], mv[3]));
      // defer-max, shfl-free common path: lane-local threshold check (log2 units)
      if (!__all(pmax - mrun[m] <= 8.f)) {
        float rm = fmaxf(pmax, __shfl_xor(pmax, 16));
        rm = fmaxf(rm, __shfl_xor(rm, 32));
        float mnew = fmaxf(mrun[m], rm);
        float sc = EXP2F(mrun[m] - mnew);
        lrun[m] *= sc;
#pragma unroll
        for (int dt = 0; dt < 8; ++dt) o[m][dt] *= sc;
        mrun[m] = mnew;
      }
      float mr = mrun[m];
      f32x4 ps = {0.f, 0.f, 0.f, 0.f};
#pragma unroll
      for (int nt = 0; nt < 4; ++nt)
#pragma unroll
        for (int r = 0; r < 4; ++r) {
          float p = EXP2F(sv[m][nt][r] - mr);
          sv[m][nt][r] = p;
          ps[r] += p;
        }
      lrun[m] += (ps[0] + ps[1]) + (ps[2] + ps[3]);   // per-lane partial sum
#pragma unroll
      for (int ks = 0; ks < 2; ++ks) {
        union { f16x8 v; hf2 hh[4]; } u;
        u.hh[0] = __builtin_amdgcn_cvt_pkrtz(sv[m][2 * ks][0], sv[m][2 * ks][1]);
        u.hh[1] = __builtin_amdgcn_cvt_pkrtz(sv[m][2 * ks][2], sv[m][2 * ks][3]);
        u.hh[2] = __builtin_amdgcn_cvt_pkrtz(sv[m][2 * ks + 1][0], sv[m][2 * ks + 1][1]);
        u.hh[3] = __builtin_amdgcn_cvt_pkrtz(sv[m][2 * ks + 1][2], sv[m][2 * ks + 1][3]);
        pf[m][ks] = u.v;
      }
    }

    __builtin_amdgcn_s_setprio(1);
#pragma unroll
    for (int ks = 0; ks < 2; ++ks)
#pragma unroll
      for (int dt = 0; dt < 8; ++dt) {
        f16x8 vf = *(const f16x8*)(vd + voff[ks][dt]);
        o[0][dt] = __builtin_amdgcn_mfma_f32_16x16x32_f16(vf, pf[0][ks], o[0][dt], 0, 0, 0);
        o[1][dt] = __builtin_amdgcn_mfma_f32_16x16x32_f16(vf, pf[1][ks], o[1][dt], 0, 0, 0);
      }
    __builtin_amdgcn_s_setprio(0);

    __syncthreads();               // all reads done before next stage overwrites
  }

  // epilogue: reduce lrun across lanes, store l-normalized O^T f16 + (m,l)
  f16* ob = opart + ((size_t)((sp * 8 + h) * 16 + qb)) * 32768;
  float* mlb = mlpart + ((size_t)((sp * 8 + h) * 16 + qb)) * 512;
#pragma unroll
  for (int m = 0; m < 2; ++m) {
    float lr = lrun[m];
    lr += __shfl_xor(lr, 16);
    lr += __shfl_xor(lr, 32);
    float rl = 1.0f / lr;
#pragma unroll
    for (int dt = 0; dt < 8; ++dt)
#pragma unroll
      for (int r = 0; r < 4; ++r)
        ob[(dt * 16 + 4 * lhi + r) * 256 + w * 32 + m * 16 + l16] = (f16)(o[m][dt][r] * rl);
    if (lhi == 0) {
      mlb[w * 32 + m * 16 + l16] = mrun[m];
      mlb[256 + w * 32 + m * 16 + l16] = lr;
    }
  }
}

// ---------------- proj GEMM with fused 4-way split-K combine -------------
__global__ __launch_bounds__(256) void proj_combine(
    const f16* __restrict__ opart, const float* __restrict__ mlpart,
    const f16* __restrict__ wpT, const float* __restrict__ b_proj,
    float* __restrict__ out)
{
  const int tid = threadIdx.x;
  const int w = tid >> 6;
  const int lane = tid & 63;
  const int l16 = lane & 15, lhi = lane >> 4;
  const int rb = blockIdx.x * 16;
  const int qb = rb >> 8;            // opart tile (256 rows)
  const int nl0 = rb & 255;          // n offset within tile

  __shared__ f16 A[16][1032];        // [n][k = h*128+d], +8 pad
  __shared__ float wl[8][16][4];     // per (h, n): c_i = n_i * rl, i = 0..3
  __shared__ float red[4][16][128];

  const float isc = 0.08838834764831845f;  // 1/sqrt(128)
  if (tid < 128) {
    int hh = tid >> 4, n = tid & 15;
    float mi[4], li[4];
#pragma unroll
    for (int i = 0; i < 4; ++i) {
      const float* ml = mlpart + ((size_t)((i * 8 + hh) * 16 + qb)) * 512 + nl0 + n;
      mi[i] = ml[0]; li[i] = ml[256];
    }
    float mt = fmaxf(fmaxf(mi[0], mi[1]), fmaxf(mi[2], mi[3]));
    float ni[4], tot = 0.f;
#pragma unroll
    for (int i = 0; i < 4; ++i) { ni[i] = EXP2F(mi[i] - mt) * li[i]; tot += ni[i]; }
    float rl = isc / tot;
#pragma unroll
    for (int i = 0; i < 4; ++i) wl[hh][n][i] = ni[i] * rl;
  }
  __syncthreads();

  {
    int d = tid >> 1, nn = (tid & 1) * 8;
#pragma unroll
    for (int hh = 0; hh < 8; ++hh) {
      float sum[8] = {};
#pragma unroll
      for (int i = 0; i < 4; ++i) {
        const f16* Oi = opart + ((size_t)((i * 8 + hh) * 16 + qb)) * 32768 + d * 256 + nl0 + nn;
        f16x8 a = *(const f16x8*)Oi;
#pragma unroll
        for (int j = 0; j < 8; ++j) sum[j] += (float)a[j] * wl[hh][nn + j][i];
      }
#pragma unroll
      for (int j = 0; j < 8; ++j) A[nn + j][hh * 128 + d] = (f16)sum[j];
    }
  }
  __syncthreads();

  f32x4 o[8];
#pragma unroll
  for (int dt = 0; dt < 8; ++dt) o[dt] = (f32x4){0.f, 0.f, 0.f, 0.f};

#pragma unroll
  for (int kb = 0; kb < 8; ++kb) {
    int k0 = w * 256 + kb * 32 + lhi * 8;
    f16x8 a = *(const f16x8*)(&A[l16][k0]);
#pragma unroll
    for (int dt = 0; dt < 8; ++dt) {
      f16x8 b = *(const f16x8*)(wpT + (size_t)(dt * 16 + l16) * 1024 + k0);
      o[dt] = __builtin_amdgcn_mfma_f32_16x16x32_f16(a, b, o[dt], 0, 0, 0);
    }
  }

#pragma unroll
  for (int dt = 0; dt < 8; ++dt)
#pragma unroll
    for (int r = 0; r < 4; ++r)
      red[w][lhi * 4 + r][dt * 16 + l16] = o[dt][r];
  __syncthreads();
#pragma unroll
  for (int i = 0; i < 8; ++i) {
    int idx = tid + 256 * i;
    int row = idx >> 7, col = idx & 127;
    float v = red[0][row][col] + red[1][row][col] + red[2][row][col]
            + red[3][row][col] + b_proj[col];
    out[(size_t)(rb + row) * 128 + col] = v;
  }
}

// ---------------- launch --------------------------------------------------
extern "C" void kernel_launch(void* const* d_in, const int* in_sizes, int n_in,
                              void* d_out, int out_size, void* d_ws, size_t ws_size,
                              hipStream_t stream) {
  const float* x      = (const float*)d_in[0];
  const float* w_qkv  = (const float*)d_in[1];
  const float* b_qkv  = (const float*)d_in[2];
  const float* w_proj = (const float*)d_in[3];
  const float* b_proj = (const float*)d_in[4];
  float* out = (float*)d_out;

  char* ws = (char*)d_ws;
  const size_t MB = 1024 * 1024;
  f16*   Qh     = (f16*)(ws);                    // 8 MiB  [h][n][d]
  f16*   Kh     = (f16*)(ws + 8 * MB);           // 8 MiB  [h][n][d]
  f16*   Vt     = (f16*)(ws + 16 * MB);          // 8 MiB  [h][d][n]
  f16*   opart  = (f16*)(ws + 24 * MB);          // 32 MiB [sp4][h][qb][d 128][n 256]
  float* mlpart = (float*)(ws + 56 * MB);        // 1 MiB
  f16*   wpT    = (f16*)(ws + 57 * MB);                       // 0.25 MiB
  f16*   wqkvT  = (f16*)(ws + 57 * MB + 256 * 1024);          // 0.75 MiB
  float* bperm  = (float*)(ws + 58 * MB);                     // 12 KiB

  hipLaunchKernelGGL(conv_weights, dim3(2048), dim3(256), 0, stream,
                     w_proj, w_qkv, b_qkv, wpT, wqkvT, bperm);
  hipLaunchKernelGGL(qkv_gemm2, dim3(24, 32), dim3(256), 0, stream,
                     x, wqkvT, bperm, Qh, Kh, Vt);
  hipLaunchKernelGGL(flash_attn, dim3(512), dim3(512), 0, stream,
                     Qh, Kh, Vt, opart, mlpart);
  hipLaunchKernelGGL(proj_combine, dim3(256), dim3(256), 0, stream,
                     opart, mlpart, wpT, b_proj, out);
}

// Round 10
// 157.882 us; speedup vs baseline: 1.9822x; 1.9822x over previous
//
#include <hip/hip_runtime.h>
#include <hip/hip_fp16.h>

// MultiHeadAttention: n=4096, e=128, H=8, fp32 in/out.
// [conv_weights] w_proj -> f16^T; w_qkv -> f16 permuted-transposed (Q pre-scaled
//                by log2(e) so flash softmax runs in exp2 units)
// [qkv_gemm2]    f16 MFMA GEMM; V stored d-major, Q/K n-major via LDS transpose
// [flash_attn]   512-thr (8 waves), split-K x4, grid 512 = 2 blocks/CU (32 KB LDS
//                single-buffered K+V). launch_bounds(512,2) -- CUDA semantics:
//                2 BLOCKS/CU -> 4 waves/SIMD with VGPR cap 128 (kernel needs ~92;
//                (512,4) capped at 64 and spilled 850 MB to scratch -- R9 lesson).
// [proj_combine] fused 4-way split-K combine (exp2-scale stats) + proj GEMM

#define N_TOK 4096
#define DH 128
#define NH 8

#define EXP2F(x) __builtin_amdgcn_exp2f(x)

typedef _Float16 f16;
typedef __attribute__((ext_vector_type(8))) _Float16 f16x8;
typedef __attribute__((ext_vector_type(2))) __fp16 hf2;
typedef __attribute__((ext_vector_type(4))) float f32x4;

#define GLD16(gsrc, ldst) __builtin_amdgcn_global_load_lds( \
    (const __attribute__((address_space(1))) void*)(gsrc), \
    (__attribute__((address_space(3))) void*)(ldst), 16, 0, 0)

// ---------------- conv: both weight matrices, one launch ------------------
__global__ __launch_bounds__(256) void conv_weights(
    const float* __restrict__ w_proj, const float* __restrict__ w_qkv,
    const float* __restrict__ b_qkv,
    f16* __restrict__ wpT, f16* __restrict__ wqkvT, float* __restrict__ bperm)
{
  int t = blockIdx.x * 256 + threadIdx.x;   // 0 .. 524287
  if (t < 131072) {
    int k = t >> 7, col = t & 127;
    wpT[col * 1024 + k] = (f16)w_proj[t];
  } else {
    t -= 131072;                            // 0 .. 393215 = 128 * 3072
    int k = t / 3072;
    int col = t - k * 3072;
    int hh = col / 384;
    int rem = col - hh * 384;
    int d = rem / 3;
    int s = rem - d * 3;
    int colp = s * 1024 + hh * 128 + d;
    float scale = (s == 0) ? 1.4426950408889634f : 1.0f;
    wqkvT[colp * 128 + k] = (f16)(w_qkv[t] * scale);
    if (k == 0) bperm[colp] = b_qkv[col] * scale;
  }
}

// ---------------- qkv GEMM v2: f16 MFMA --------------------------------
__global__ __launch_bounds__(256) void qkv_gemm2(
    const float* __restrict__ x, const f16* __restrict__ wqkvT,
    const float* __restrict__ bperm,
    f16* __restrict__ Qh, f16* __restrict__ Kh, f16* __restrict__ Vt)
{
  const int cb = blockIdx.x;               // 0..23: s = cb>>3, h = cb&7
  const int rb = blockIdx.y;               // 0..31: rows rb*128
  const int tid = threadIdx.x;
  const int w = tid >> 6, lane = tid & 63;
  const int l16 = lane & 15, lhi = lane >> 4;
  const int s = cb >> 3, h = cb & 7;

  f16x8 xf[2][4];
#pragma unroll
  for (int m = 0; m < 2; ++m)
#pragma unroll
    for (int kt = 0; kt < 4; ++kt) {
      const float* xp = x + (size_t)(rb * 128 + w * 32 + m * 16 + l16) * 128 + kt * 32 + lhi * 8;
      f32x4 x0 = *(const f32x4*)xp, x1 = *(const f32x4*)(xp + 4);
      f16x8 v;
#pragma unroll
      for (int j = 0; j < 4; ++j) { v[j] = (f16)x0[j]; v[4 + j] = (f16)x1[j]; }
      xf[m][kt] = v;
    }

  f32x4 acc[8][2];
#pragma unroll
  for (int nt = 0; nt < 8; ++nt)
#pragma unroll
    for (int m = 0; m < 2; ++m) acc[nt][m] = (f32x4){0.f, 0.f, 0.f, 0.f};

#pragma unroll
  for (int nt = 0; nt < 8; ++nt)
#pragma unroll
    for (int kt = 0; kt < 4; ++kt) {
      f16x8 wf = *(const f16x8*)(wqkvT + (size_t)(cb * 128 + nt * 16 + l16) * 128 + kt * 32 + lhi * 8);
      acc[nt][0] = __builtin_amdgcn_mfma_f32_16x16x32_f16(wf, xf[0][kt], acc[nt][0], 0, 0, 0);
      acc[nt][1] = __builtin_amdgcn_mfma_f32_16x16x32_f16(wf, xf[1][kt], acc[nt][1], 0, 0, 0);
    }

#pragma unroll
  for (int nt = 0; nt < 8; ++nt) {
    f32x4 bb = *(const f32x4*)(bperm + cb * 128 + nt * 16 + 4 * lhi);
#pragma unroll
    for (int m = 0; m < 2; ++m) acc[nt][m] += bb;
  }

  if (s == 2) {            // V: direct d-major store [h*128+d][n]
#pragma unroll
    for (int nt = 0; nt < 8; ++nt)
#pragma unroll
      for (int m = 0; m < 2; ++m)
#pragma unroll
        for (int r = 0; r < 4; ++r)
          Vt[(size_t)(h * 128 + nt * 16 + 4 * lhi + r) * N_TOK + rb * 128 + w * 32 + m * 16 + l16] =
              (f16)acc[nt][m][r];
  } else {                 // Q/K: LDS transpose -> n-major [n][d]
    __shared__ f16 tr[128][136];
#pragma unroll
    for (int nt = 0; nt < 8; ++nt)
#pragma unroll
      for (int m = 0; m < 2; ++m)
#pragma unroll
        for (int r = 0; r < 4; ++r)
          tr[w * 32 + m * 16 + l16][nt * 16 + 4 * lhi + r] = (f16)acc[nt][m][r];
    __syncthreads();
    f16* dst = (s == 0 ? Qh : Kh) + (size_t)(h * N_TOK + rb * 128) * 128;
    int r = tid >> 1, dh = (tid & 1) * 64;
#pragma unroll
    for (int i = 0; i < 8; ++i)
      *(f16x8*)(dst + r * 128 + dh + i * 8) = *(const f16x8*)(&tr[r][dh + i * 8]);
  }
}

// ---------------- flash attention: 8 waves, split-K x4, 32 KB LDS --------
// grid 512: h = bid&7 (XCD pin), sp = (bid>>3)&3, qb = bid>>5 (0..15).
// Single-buffered K (16K) + V (16K); 2 blocks/CU -> cross-block TLP.
__global__ __launch_bounds__(512, 2) void flash_attn(
    const f16* __restrict__ Qh, const f16* __restrict__ Kh,
    const f16* __restrict__ Vt, f16* __restrict__ opart, float* __restrict__ mlpart)
{
  const int bid = blockIdx.x;
  const int h = bid & 7, sp = (bid >> 3) & 3, qb = bid >> 5;
  const int tid = threadIdx.x;
  const int w = tid >> 6, lane = tid & 63;
  const int l16 = lane & 15, lhi = lane >> 4;

  __shared__ __align__(16) char smem[32768];   // K @0 (16K), V @16K

  f16x8 qf[2][4];
#pragma unroll
  for (int m = 0; m < 2; ++m)
#pragma unroll
    for (int kt = 0; kt < 4; ++kt)
      qf[m][kt] = *(const f16x8*)(Qh +
          (size_t)(h * N_TOK + qb * 256 + w * 32 + m * 16 + l16) * DH + kt * 32 + lhi * 8);

  // K A-row permutation pi = 32*(nt>>1) + 8*(i>>2) + 4*(nt&1) + (i&3); XOR swizzle
  int koff[4][4], voff[2][8];
#pragma unroll
  for (int nt = 0; nt < 4; ++nt) {
    int row = 32 * (nt >> 1) + 8 * (l16 >> 2) + 4 * (nt & 1) + (l16 & 3);
    int fk = (row & 3) | ((row & 8) >> 1);
#pragma unroll
    for (int kt = 0; kt < 4; ++kt)
      koff[nt][kt] = row * 256 + ((kt * 4 + lhi) ^ fk) * 16;
  }
#pragma unroll
  for (int ks = 0; ks < 2; ++ks)
#pragma unroll
    for (int dt = 0; dt < 8; ++dt) {
      int rowv = dt * 16 + l16;
      voff[ks][dt] = rowv * 128 + (((ks * 4 + lhi) ^ (rowv & 7))) * 16;
    }

  f32x4 o[2][8];
#pragma unroll
  for (int m = 0; m < 2; ++m)
#pragma unroll
    for (int dt = 0; dt < 8; ++dt) o[m][dt] = (f32x4){0.f, 0.f, 0.f, 0.f};
  float mrun[2] = {-3e38f, -3e38f}, lrun[2] = {0.f, 0.f};   // lrun: per-lane partial

  const f16* Kgh = Kh + (size_t)h * N_TOK * DH;
  const f16* Vgh = Vt + (size_t)h * DH * N_TOK;

  // wave w stages 4 x GLD16 (K chunks 2w,2w+1 + V chunks 2w,2w+1), disjoint per wave
  auto stage = [&](int kb) {
    char* kd = smem;
    char* vd = smem + 16384;
#pragma unroll
    for (int c2 = 0; c2 < 2; ++c2) {
      int c = w * 2 + c2;   // 0..15
      {
        int row = c * 4 + (lane >> 4);
        int fk = (row & 3) | ((row & 8) >> 1);
        const f16* src = Kgh + (size_t)(kb * 64 + row) * DH + ((lane & 15) ^ fk) * 8;
        GLD16(src, kd + c * 1024);
      }
      {
        int row = c * 8 + (lane >> 3);
        const f16* src = Vgh + (size_t)row * N_TOK + kb * 64 + ((lane & 7) ^ (row & 7)) * 8;
        GLD16(src, vd + c * 1024);
      }
    }
  };

  const int kb0 = sp * 16;
  const char* kd = smem;
  const char* vd = smem + 16384;

  for (int it = 0; it < 16; ++it) {
    stage(kb0 + it);
    __syncthreads();               // stage writes landed (vmcnt(0) + barrier)

    f32x4 sv[2][4];
    __builtin_amdgcn_s_setprio(1);
#pragma unroll
    for (int nt = 0; nt < 4; ++nt) {
      f32x4 a0 = {0.f, 0.f, 0.f, 0.f}, a1 = {0.f, 0.f, 0.f, 0.f};
#pragma unroll
      for (int kt = 0; kt < 4; ++kt) {
        f16x8 kf = *(const f16x8*)(kd + koff[nt][kt]);
        a0 = __builtin_amdgcn_mfma_f32_16x16x32_f16(kf, qf[0][kt], a0, 0, 0, 0);
        a1 = __builtin_amdgcn_mfma_f32_16x16x32_f16(kf, qf[1][kt], a1, 0, 0, 0);
      }
      sv[0][nt] = a0; sv[1][nt] = a1;
    }
    __builtin_amdgcn_s_setprio(0);

    f16x8 pf[2][2];
#pragma unroll
    for (int m = 0; m < 2; ++m) {
      f32x4 mv;
#pragma unroll
      for (int r = 0; r < 4; ++r)
        mv[r] = fmaxf(fmaxf(sv[m][0][r], sv[m][1][r]), fmaxf(sv[m][2][r], sv[m][3][r]));
      float pmax = fmaxf(fmaxf(mv[0], mv[1]), fmaxf(mv[2], mv[3]));
      // defer-max, shfl-free common path: lane-local threshold check (log2 units)
      if (!__all(pmax - mrun[m] <= 8.f)) {
        float rm = fmaxf(pmax, __shfl_xor(pmax, 16));
        rm = fmaxf(rm, __shfl_xor(rm, 32));
        float mnew = fmaxf(mrun[m], rm);
        float sc = EXP2F(mrun[m] - mnew);
        lrun[m] *= sc;
#pragma unroll
        for (int dt = 0; dt < 8; ++dt) o[m][dt] *= sc;
        mrun[m] = mnew;
      }
      float mr = mrun[m];
      f32x4 ps = {0.f, 0.f, 0.f, 0.f};
#pragma unroll
      for (int nt = 0; nt < 4; ++nt)
#pragma unroll
        for (int r = 0; r < 4; ++r) {
          float p = EXP2F(sv[m][nt][r] - mr);
          sv[m][nt][r] = p;
          ps[r] += p;
        }
      lrun[m] += (ps[0] + ps[1]) + (ps[2] + ps[3]);   // per-lane partial sum
#pragma unroll
      for (int ks = 0; ks < 2; ++ks) {
        union { f16x8 v; hf2 hh[4]; } u;
        u.hh[0] = __builtin_amdgcn_cvt_pkrtz(sv[m][2 * ks][0], sv[m][2 * ks][1]);
        u.hh[1] = __builtin_amdgcn_cvt_pkrtz(sv[m][2 * ks][2], sv[m][2 * ks][3]);
        u.hh[2] = __builtin_amdgcn_cvt_pkrtz(sv[m][2 * ks + 1][0], sv[m][2 * ks + 1][1]);
        u.hh[3] = __builtin_amdgcn_cvt_pkrtz(sv[m][2 * ks + 1][2], sv[m][2 * ks + 1][3]);
        pf[m][ks] = u.v;
      }
    }

    __builtin_amdgcn_s_setprio(1);
#pragma unroll
    for (int ks = 0; ks < 2; ++ks)
#pragma unroll
      for (int dt = 0; dt < 8; ++dt) {
        f16x8 vf = *(const f16x8*)(vd + voff[ks][dt]);
        o[0][dt] = __builtin_amdgcn_mfma_f32_16x16x32_f16(vf, pf[0][ks], o[0][dt], 0, 0, 0);
        o[1][dt] = __builtin_amdgcn_mfma_f32_16x16x32_f16(vf, pf[1][ks], o[1][dt], 0, 0, 0);
      }
    __builtin_amdgcn_s_setprio(0);

    __syncthreads();               // all reads done before next stage overwrites
  }

  // epilogue: reduce lrun across lanes, store l-normalized O^T f16 + (m,l)
  f16* ob = opart + ((size_t)((sp * 8 + h) * 16 + qb)) * 32768;
  float* mlb = mlpart + ((size_t)((sp * 8 + h) * 16 + qb)) * 512;
#pragma unroll
  for (int m = 0; m < 2; ++m) {
    float lr = lrun[m];
    lr += __shfl_xor(lr, 16);
    lr += __shfl_xor(lr, 32);
    float rl = 1.0f / lr;
#pragma unroll
    for (int dt = 0; dt < 8; ++dt)
#pragma unroll
      for (int r = 0; r < 4; ++r)
        ob[(dt * 16 + 4 * lhi + r) * 256 + w * 32 + m * 16 + l16] = (f16)(o[m][dt][r] * rl);
    if (lhi == 0) {
      mlb[w * 32 + m * 16 + l16] = mrun[m];
      mlb[256 + w * 32 + m * 16 + l16] = lr;
    }
  }
}

// ---------------- proj GEMM with fused 4-way split-K combine -------------
__global__ __launch_bounds__(256) void proj_combine(
    const f16* __restrict__ opart, const float* __restrict__ mlpart,
    const f16* __restrict__ wpT, const float* __restrict__ b_proj,
    float* __restrict__ out)
{
  const int tid = threadIdx.x;
  const int w = tid >> 6;
  const int lane = tid & 63;
  const int l16 = lane & 15, lhi = lane >> 4;
  const int rb = blockIdx.x * 16;
  const int qb = rb >> 8;            // opart tile (256 rows)
  const int nl0 = rb & 255;          // n offset within tile

  __shared__ f16 A[16][1032];        // [n][k = h*128+d], +8 pad
  __shared__ float wl[8][16][4];     // per (h, n): c_i = n_i * rl, i = 0..3
  __shared__ float red[4][16][128];

  const float isc = 0.08838834764831845f;  // 1/sqrt(128)
  if (tid < 128) {
    int hh = tid >> 4, n = tid & 15;
    float mi[4], li[4];
#pragma unroll
    for (int i = 0; i < 4; ++i) {
      const float* ml = mlpart + ((size_t)((i * 8 + hh) * 16 + qb)) * 512 + nl0 + n;
      mi[i] = ml[0]; li[i] = ml[256];
    }
    float mt = fmaxf(fmaxf(mi[0], mi[1]), fmaxf(mi[2], mi[3]));
    float ni[4], tot = 0.f;
#pragma unroll
    for (int i = 0; i < 4; ++i) { ni[i] = EXP2F(mi[i] - mt) * li[i]; tot += ni[i]; }
    float rl = isc / tot;
#pragma unroll
    for (int i = 0; i < 4; ++i) wl[hh][n][i] = ni[i] * rl;
  }
  __syncthreads();

  {
    int d = tid >> 1, nn = (tid & 1) * 8;
#pragma unroll
    for (int hh = 0; hh < 8; ++hh) {
      float sum[8] = {};
#pragma unroll
      for (int i = 0; i < 4; ++i) {
        const f16* Oi = opart + ((size_t)((i * 8 + hh) * 16 + qb)) * 32768 + d * 256 + nl0 + nn;
        f16x8 a = *(const f16x8*)Oi;
#pragma unroll
        for (int j = 0; j < 8; ++j) sum[j] += (float)a[j] * wl[hh][nn + j][i];
      }
#pragma unroll
      for (int j = 0; j < 8; ++j) A[nn + j][hh * 128 + d] = (f16)sum[j];
    }
  }
  __syncthreads();

  f32x4 o[8];
#pragma unroll
  for (int dt = 0; dt < 8; ++dt) o[dt] = (f32x4){0.f, 0.f, 0.f, 0.f};

#pragma unroll
  for (int kb = 0; kb < 8; ++kb) {
    int k0 = w * 256 + kb * 32 + lhi * 8;
    f16x8 a = *(const f16x8*)(&A[l16][k0]);
#pragma unroll
    for (int dt = 0; dt < 8; ++dt) {
      f16x8 b = *(const f16x8*)(wpT + (size_t)(dt * 16 + l16) * 1024 + k0);
      o[dt] = __builtin_amdgcn_mfma_f32_16x16x32_f16(a, b, o[dt], 0, 0, 0);
    }
  }

#pragma unroll
  for (int dt = 0; dt < 8; ++dt)
#pragma unroll
    for (int r = 0; r < 4; ++r)
      red[w][lhi * 4 + r][dt * 16 + l16] = o[dt][r];
  __syncthreads();
#pragma unroll
  for (int i = 0; i < 8; ++i) {
    int idx = tid + 256 * i;
    int row = idx >> 7, col = idx & 127;
    float v = red[0][row][col] + red[1][row][col] + red[2][row][col]
            + red[3][row][col] + b_proj[col];
    out[(size_t)(rb + row) * 128 + col] = v;
  }
}

// ---------------- launch --------------------------------------------------
extern "C" void kernel_launch(void* const* d_in, const int* in_sizes, int n_in,
                              void* d_out, int out_size, void* d_ws, size_t ws_size,
                              hipStream_t stream) {
  const float* x      = (const float*)d_in[0];
  const float* w_qkv  = (const float*)d_in[1];
  const float* b_qkv  = (const float*)d_in[2];
  const float* w_proj = (const float*)d_in[3];
  const float* b_proj = (const float*)d_in[4];
  float* out = (float*)d_out;

  char* ws = (char*)d_ws;
  const size_t MB = 1024 * 1024;
  f16*   Qh     = (f16*)(ws);                    // 8 MiB  [h][n][d]
  f16*   Kh     = (f16*)(ws + 8 * MB);           // 8 MiB  [h][n][d]
  f16*   Vt     = (f16*)(ws + 16 * MB);          // 8 MiB  [h][d][n]
  f16*   opart  = (f16*)(ws + 24 * MB);          // 32 MiB [sp4][h][qb][d 128][n 256]
  float* mlpart = (float*)(ws + 56 * MB);        // 1 MiB
  f16*   wpT    = (f16*)(ws + 57 * MB);                       // 0.25 MiB
  f16*   wqkvT  = (f16*)(ws + 57 * MB + 256 * 1024);          // 0.75 MiB
  float* bperm  = (float*)(ws + 58 * MB);                     // 12 KiB

  hipLaunchKernelGGL(conv_weights, dim3(2048), dim3(256), 0, stream,
                     w_proj, w_qkv, b_qkv, wpT, wqkvT, bperm);
  hipLaunchKernelGGL(qkv_gemm2, dim3(24, 32), dim3(256), 0, stream,
                     x, wqkvT, bperm, Qh, Kh, Vt);
  hipLaunchKernelGGL(flash_attn, dim3(512), dim3(512), 0, stream,
                     Qh, Kh, Vt, opart, mlpart);
  hipLaunchKernelGGL(proj_combine, dim3(256), dim3(256), 0, stream,
                     opart, mlpart, wpT, b_proj, out);
}

// Round 12
// 136.453 us; speedup vs baseline: 2.2935x; 1.1570x over previous
//
#include <hip/hip_runtime.h>
#include <hip/hip_fp16.h>

// MultiHeadAttention: n=4096, e=128, H=8, fp32 in/out.
// [conv_weights] w_proj -> f16^T; w_qkv -> f16 permuted-transposed (Q pre-scaled
//                by log2(e) so flash softmax runs in exp2 units)
// [qkv_gemm2]    f16 MFMA GEMM; V stored d-major, Q/K n-major via LDS transpose
// [flash_attn]   256-thr blocks (4 waves), split-K x3 over 64 k-tiles (21/21/22 --
//                R11 bug: partitioned 32 tiles, dropping half the keys), grid 768 =
//                3 blocks/CU -> 12 waves/CU. 32 KB single-buffered LDS; cross-block
//                TLP covers stage waits.
// [proj_combine] fused 3-way split-K combine (exp2-scale stats) + proj GEMM

#define N_TOK 4096
#define DH 128
#define NH 8

#define EXP2F(x) __builtin_amdgcn_exp2f(x)

typedef _Float16 f16;
typedef __attribute__((ext_vector_type(8))) _Float16 f16x8;
typedef __attribute__((ext_vector_type(2))) __fp16 hf2;
typedef __attribute__((ext_vector_type(4))) float f32x4;

#define GLD16(gsrc, ldst) __builtin_amdgcn_global_load_lds( \
    (const __attribute__((address_space(1))) void*)(gsrc), \
    (__attribute__((address_space(3))) void*)(ldst), 16, 0, 0)

// ---------------- conv: both weight matrices, one launch ------------------
__global__ __launch_bounds__(256) void conv_weights(
    const float* __restrict__ w_proj, const float* __restrict__ w_qkv,
    const float* __restrict__ b_qkv,
    f16* __restrict__ wpT, f16* __restrict__ wqkvT, float* __restrict__ bperm)
{
  int t = blockIdx.x * 256 + threadIdx.x;   // 0 .. 524287
  if (t < 131072) {
    int k = t >> 7, col = t & 127;
    wpT[col * 1024 + k] = (f16)w_proj[t];
  } else {
    t -= 131072;                            // 0 .. 393215 = 128 * 3072
    int k = t / 3072;
    int col = t - k * 3072;
    int hh = col / 384;
    int rem = col - hh * 384;
    int d = rem / 3;
    int s = rem - d * 3;
    int colp = s * 1024 + hh * 128 + d;
    float scale = (s == 0) ? 1.4426950408889634f : 1.0f;
    wqkvT[colp * 128 + k] = (f16)(w_qkv[t] * scale);
    if (k == 0) bperm[colp] = b_qkv[col] * scale;
  }
}

// ---------------- qkv GEMM v2: f16 MFMA --------------------------------
__global__ __launch_bounds__(256) void qkv_gemm2(
    const float* __restrict__ x, const f16* __restrict__ wqkvT,
    const float* __restrict__ bperm,
    f16* __restrict__ Qh, f16* __restrict__ Kh, f16* __restrict__ Vt)
{
  const int cb = blockIdx.x;               // 0..23: s = cb>>3, h = cb&7
  const int rb = blockIdx.y;               // 0..31: rows rb*128
  const int tid = threadIdx.x;
  const int w = tid >> 6, lane = tid & 63;
  const int l16 = lane & 15, lhi = lane >> 4;
  const int s = cb >> 3, h = cb & 7;

  f16x8 xf[2][4];
#pragma unroll
  for (int m = 0; m < 2; ++m)
#pragma unroll
    for (int kt = 0; kt < 4; ++kt) {
      const float* xp = x + (size_t)(rb * 128 + w * 32 + m * 16 + l16) * 128 + kt * 32 + lhi * 8;
      f32x4 x0 = *(const f32x4*)xp, x1 = *(const f32x4*)(xp + 4);
      f16x8 v;
#pragma unroll
      for (int j = 0; j < 4; ++j) { v[j] = (f16)x0[j]; v[4 + j] = (f16)x1[j]; }
      xf[m][kt] = v;
    }

  f32x4 acc[8][2];
#pragma unroll
  for (int nt = 0; nt < 8; ++nt)
#pragma unroll
    for (int m = 0; m < 2; ++m) acc[nt][m] = (f32x4){0.f, 0.f, 0.f, 0.f};

#pragma unroll
  for (int nt = 0; nt < 8; ++nt)
#pragma unroll
    for (int kt = 0; kt < 4; ++kt) {
      f16x8 wf = *(const f16x8*)(wqkvT + (size_t)(cb * 128 + nt * 16 + l16) * 128 + kt * 32 + lhi * 8);
      acc[nt][0] = __builtin_amdgcn_mfma_f32_16x16x32_f16(wf, xf[0][kt], acc[nt][0], 0, 0, 0);
      acc[nt][1] = __builtin_amdgcn_mfma_f32_16x16x32_f16(wf, xf[1][kt], acc[nt][1], 0, 0, 0);
    }

#pragma unroll
  for (int nt = 0; nt < 8; ++nt) {
    f32x4 bb = *(const f32x4*)(bperm + cb * 128 + nt * 16 + 4 * lhi);
#pragma unroll
    for (int m = 0; m < 2; ++m) acc[nt][m] += bb;
  }

  if (s == 2) {            // V: direct d-major store [h*128+d][n]
#pragma unroll
    for (int nt = 0; nt < 8; ++nt)
#pragma unroll
      for (int m = 0; m < 2; ++m)
#pragma unroll
        for (int r = 0; r < 4; ++r)
          Vt[(size_t)(h * 128 + nt * 16 + 4 * lhi + r) * N_TOK + rb * 128 + w * 32 + m * 16 + l16] =
              (f16)acc[nt][m][r];
  } else {                 // Q/K: LDS transpose -> n-major [n][d]
    __shared__ f16 tr[128][136];
#pragma unroll
    for (int nt = 0; nt < 8; ++nt)
#pragma unroll
      for (int m = 0; m < 2; ++m)
#pragma unroll
        for (int r = 0; r < 4; ++r)
          tr[w * 32 + m * 16 + l16][nt * 16 + 4 * lhi + r] = (f16)acc[nt][m][r];
    __syncthreads();
    f16* dst = (s == 0 ? Qh : Kh) + (size_t)(h * N_TOK + rb * 128) * 128;
    int r = tid >> 1, dh = (tid & 1) * 64;
#pragma unroll
    for (int i = 0; i < 8; ++i)
      *(f16x8*)(dst + r * 128 + dh + i * 8) = *(const f16x8*)(&tr[r][dh + i * 8]);
  }
}

// ---------------- flash attention: 4 waves, split-K x3, 32 KB LDS --------
// grid 768: h = bid&7 (XCD pin), sp = (bid>>3)%3, qb = (bid>>3)/3 (0..31).
// Block covers 128 q-rows; single-buffered K (16K) + V (16K); 3 blocks/CU.
__global__ __launch_bounds__(256, 3) void flash_attn(
    const f16* __restrict__ Qh, const f16* __restrict__ Kh,
    const f16* __restrict__ Vt, f16* __restrict__ opart, float* __restrict__ mlpart)
{
  const int bid = blockIdx.x;
  const int h = bid & 7;
  const int rem8 = bid >> 3;
  const int sp = rem8 % 3, qb = rem8 / 3;
  const int tid = threadIdx.x;
  const int w = tid >> 6, lane = tid & 63;
  const int l16 = lane & 15, lhi = lane >> 4;

  __shared__ __align__(16) char smem[32768];   // K @0 (16K), V @16K

  f16x8 qf[2][4];
#pragma unroll
  for (int m = 0; m < 2; ++m)
#pragma unroll
    for (int kt = 0; kt < 4; ++kt)
      qf[m][kt] = *(const f16x8*)(Qh +
          (size_t)(h * N_TOK + qb * 128 + w * 32 + m * 16 + l16) * DH + kt * 32 + lhi * 8);

  // K A-row permutation pi = 32*(nt>>1) + 8*(i>>2) + 4*(nt&1) + (i&3); XOR swizzle
  int koff[4][4], voff[2][8];
#pragma unroll
  for (int nt = 0; nt < 4; ++nt) {
    int row = 32 * (nt >> 1) + 8 * (l16 >> 2) + 4 * (nt & 1) + (l16 & 3);
    int fk = (row & 3) | ((row & 8) >> 1);
#pragma unroll
    for (int kt = 0; kt < 4; ++kt)
      koff[nt][kt] = row * 256 + ((kt * 4 + lhi) ^ fk) * 16;
  }
#pragma unroll
  for (int ks = 0; ks < 2; ++ks)
#pragma unroll
    for (int dt = 0; dt < 8; ++dt) {
      int rowv = dt * 16 + l16;
      voff[ks][dt] = rowv * 128 + (((ks * 4 + lhi) ^ (rowv & 7))) * 16;
    }

  f32x4 o[2][8];
#pragma unroll
  for (int m = 0; m < 2; ++m)
#pragma unroll
    for (int dt = 0; dt < 8; ++dt) o[m][dt] = (f32x4){0.f, 0.f, 0.f, 0.f};
  float mrun[2] = {-3e38f, -3e38f}, lrun[2] = {0.f, 0.f};   // lrun: per-lane partial

  const f16* Kgh = Kh + (size_t)h * N_TOK * DH;
  const f16* Vgh = Vt + (size_t)h * DH * N_TOK;

  // wave w stages 8 x GLD16: K chunks 4w..4w+3 + V chunks 4w..4w+3 (disjoint)
  auto stage = [&](int kb) {
    char* kd = smem;
    char* vd = smem + 16384;
#pragma unroll
    for (int c4 = 0; c4 < 4; ++c4) {
      int c = w * 4 + c4;   // 0..15
      {
        int row = c * 4 + (lane >> 4);
        int fk = (row & 3) | ((row & 8) >> 1);
        const f16* src = Kgh + (size_t)(kb * 64 + row) * DH + ((lane & 15) ^ fk) * 8;
        GLD16(src, kd + c * 1024);
      }
      {
        int row = c * 8 + (lane >> 3);
        const f16* src = Vgh + (size_t)row * N_TOK + kb * 64 + ((lane & 7) ^ (row & 7)) * 8;
        GLD16(src, vd + c * 1024);
      }
    }
  };

  // split over ALL 64 k-tiles: {0..20, 21..41, 42..63} (R11 bug: used 32)
  const int kb0 = (sp * 64) / 3;        // 0, 21, 42
  const int kb1 = ((sp + 1) * 64) / 3;  // 21, 42, 64
  const char* kd = smem;
  const char* vd = smem + 16384;

  for (int kb = kb0; kb < kb1; ++kb) {
    stage(kb);
    __syncthreads();               // stage writes landed (vmcnt(0) + barrier)

    f32x4 sv[2][4];
    __builtin_amdgcn_s_setprio(1);
#pragma unroll
    for (int nt = 0; nt < 4; ++nt) {
      f32x4 a0 = {0.f, 0.f, 0.f, 0.f}, a1 = {0.f, 0.f, 0.f, 0.f};
#pragma unroll
      for (int kt = 0; kt < 4; ++kt) {
        f16x8 kf = *(const f16x8*)(kd + koff[nt][kt]);
        a0 = __builtin_amdgcn_mfma_f32_16x16x32_f16(kf, qf[0][kt], a0, 0, 0, 0);
        a1 = __builtin_amdgcn_mfma_f32_16x16x32_f16(kf, qf[1][kt], a1, 0, 0, 0);
      }
      sv[0][nt] = a0; sv[1][nt] = a1;
    }
    __builtin_amdgcn_s_setprio(0);

    f16x8 pf[2][2];
#pragma unroll
    for (int m = 0; m < 2; ++m) {
      f32x4 mv;
#pragma unroll
      for (int r = 0; r < 4; ++r)
        mv[r] = fmaxf(fmaxf(sv[m][0][r], sv[m][1][r]), fmaxf(sv[m][2][r], sv[m][3][r]));
      float pmax = fmaxf(fmaxf(mv[0], mv[1]), fmaxf(mv[2], mv[3]));
      // defer-max, shfl-free common path: lane-local threshold check (log2 units)
      if (!__all(pmax - mrun[m] <= 8.f)) {
        float rm = fmaxf(pmax, __shfl_xor(pmax, 16));
        rm = fmaxf(rm, __shfl_xor(rm, 32));
        float mnew = fmaxf(mrun[m], rm);
        float sc = EXP2F(mrun[m] - mnew);
        lrun[m] *= sc;
#pragma unroll
        for (int dt = 0; dt < 8; ++dt) o[m][dt] *= sc;
        mrun[m] = mnew;
      }
      float mr = mrun[m];
      f32x4 ps = {0.f, 0.f, 0.f, 0.f};
#pragma unroll
      for (int nt = 0; nt < 4; ++nt)
#pragma unroll
        for (int r = 0; r < 4; ++r) {
          float p = EXP2F(sv[m][nt][r] - mr);
          sv[m][nt][r] = p;
          ps[r] += p;
        }
      lrun[m] += (ps[0] + ps[1]) + (ps[2] + ps[3]);   // per-lane partial sum
#pragma unroll
      for (int ks = 0; ks < 2; ++ks) {
        union { f16x8 v; hf2 hh[4]; } u;
        u.hh[0] = __builtin_amdgcn_cvt_pkrtz(sv[m][2 * ks][0], sv[m][2 * ks][1]);
        u.hh[1] = __builtin_amdgcn_cvt_pkrtz(sv[m][2 * ks][2], sv[m][2 * ks][3]);
        u.hh[2] = __builtin_amdgcn_cvt_pkrtz(sv[m][2 * ks + 1][0], sv[m][2 * ks + 1][1]);
        u.hh[3] = __builtin_amdgcn_cvt_pkrtz(sv[m][2 * ks + 1][2], sv[m][2 * ks + 1][3]);
        pf[m][ks] = u.v;
      }
    }

    __builtin_amdgcn_s_setprio(1);
#pragma unroll
    for (int ks = 0; ks < 2; ++ks)
#pragma unroll
      for (int dt = 0; dt < 8; ++dt) {
        f16x8 vf = *(const f16x8*)(vd + voff[ks][dt]);
        o[0][dt] = __builtin_amdgcn_mfma_f32_16x16x32_f16(vf, pf[0][ks], o[0][dt], 0, 0, 0);
        o[1][dt] = __builtin_amdgcn_mfma_f32_16x16x32_f16(vf, pf[1][ks], o[1][dt], 0, 0, 0);
      }
    __builtin_amdgcn_s_setprio(0);

    __syncthreads();               // all reads done before next stage overwrites
  }

  // epilogue: reduce lrun across lanes, store l-normalized O^T f16 + (m,l)
  f16* ob = opart + ((size_t)((sp * 8 + h) * 32 + qb)) * 16384;   // [128 d][128 n]
  float* mlb = mlpart + ((size_t)((sp * 8 + h) * 32 + qb)) * 256;
#pragma unroll
  for (int m = 0; m < 2; ++m) {
    float lr = lrun[m];
    lr += __shfl_xor(lr, 16);
    lr += __shfl_xor(lr, 32);
    float rl = 1.0f / lr;
#pragma unroll
    for (int dt = 0; dt < 8; ++dt)
#pragma unroll
      for (int r = 0; r < 4; ++r)
        ob[(dt * 16 + 4 * lhi + r) * 128 + w * 32 + m * 16 + l16] = (f16)(o[m][dt][r] * rl);
    if (lhi == 0) {
      mlb[w * 32 + m * 16 + l16] = mrun[m];
      mlb[128 + w * 32 + m * 16 + l16] = lr;
    }
  }
}

// ---------------- proj GEMM with fused 3-way split-K combine -------------
__global__ __launch_bounds__(256) void proj_combine(
    const f16* __restrict__ opart, const float* __restrict__ mlpart,
    const f16* __restrict__ wpT, const float* __restrict__ b_proj,
    float* __restrict__ out)
{
  const int tid = threadIdx.x;
  const int w = tid >> 6;
  const int lane = tid & 63;
  const int l16 = lane & 15, lhi = lane >> 4;
  const int rb = blockIdx.x * 16;
  const int qb = rb >> 7;            // opart tile (128 rows)
  const int nl0 = rb & 127;          // n offset within tile

  __shared__ f16 A[16][1032];        // [n][k = h*128+d], +8 pad
  __shared__ float wl[8][16][3];     // per (h, n): c_i = n_i * rl, i = 0..2
  __shared__ float red[4][16][128];

  const float isc = 0.08838834764831845f;  // 1/sqrt(128)
  if (tid < 128) {
    int hh = tid >> 4, n = tid & 15;
    float mi[3], li[3];
#pragma unroll
    for (int i = 0; i < 3; ++i) {
      const float* ml = mlpart + ((size_t)((i * 8 + hh) * 32 + qb)) * 256 + nl0 + n;
      mi[i] = ml[0]; li[i] = ml[128];
    }
    float mt = fmaxf(fmaxf(mi[0], mi[1]), mi[2]);
    float ni[3], tot = 0.f;
#pragma unroll
    for (int i = 0; i < 3; ++i) { ni[i] = EXP2F(mi[i] - mt) * li[i]; tot += ni[i]; }
    float rl = isc / tot;
#pragma unroll
    for (int i = 0; i < 3; ++i) wl[hh][n][i] = ni[i] * rl;
  }
  __syncthreads();

  {
    int d = tid >> 1, nn = (tid & 1) * 8;
#pragma unroll
    for (int hh = 0; hh < 8; ++hh) {
      float sum[8] = {};
#pragma unroll
      for (int i = 0; i < 3; ++i) {
        const f16* Oi = opart + ((size_t)((i * 8 + hh) * 32 + qb)) * 16384 + d * 128 + nl0 + nn;
        f16x8 a = *(const f16x8*)Oi;
#pragma unroll
        for (int j = 0; j < 8; ++j) sum[j] += (float)a[j] * wl[hh][nn + j][i];
      }
#pragma unroll
      for (int j = 0; j < 8; ++j) A[nn + j][hh * 128 + d] = (f16)sum[j];
    }
  }
  __syncthreads();

  f32x4 o[8];
#pragma unroll
  for (int dt = 0; dt < 8; ++dt) o[dt] = (f32x4){0.f, 0.f, 0.f, 0.f};

#pragma unroll
  for (int kb = 0; kb < 8; ++kb) {
    int k0 = w * 256 + kb * 32 + lhi * 8;
    f16x8 a = *(const f16x8*)(&A[l16][k0]);
#pragma unroll
    for (int dt = 0; dt < 8; ++dt) {
      f16x8 b = *(const f16x8*)(wpT + (size_t)(dt * 16 + l16) * 1024 + k0);
      o[dt] = __builtin_amdgcn_mfma_f32_16x16x32_f16(a, b, o[dt], 0, 0, 0);
    }
  }

#pragma unroll
  for (int dt = 0; dt < 8; ++dt)
#pragma unroll
    for (int r = 0; r < 4; ++r)
      red[w][lhi * 4 + r][dt * 16 + l16] = o[dt][r];
  __syncthreads();
#pragma unroll
  for (int i = 0; i < 8; ++i) {
    int idx = tid + 256 * i;
    int row = idx >> 7, col = idx & 127;
    float v = red[0][row][col] + red[1][row][col] + red[2][row][col]
            + red[3][row][col] + b_proj[col];
    out[(size_t)(rb + row) * 128 + col] = v;
  }
}

// ---------------- launch --------------------------------------------------
extern "C" void kernel_launch(void* const* d_in, const int* in_sizes, int n_in,
                              void* d_out, int out_size, void* d_ws, size_t ws_size,
                              hipStream_t stream) {
  const float* x      = (const float*)d_in[0];
  const float* w_qkv  = (const float*)d_in[1];
  const float* b_qkv  = (const float*)d_in[2];
  const float* w_proj = (const float*)d_in[3];
  const float* b_proj = (const float*)d_in[4];
  float* out = (float*)d_out;

  char* ws = (char*)d_ws;
  const size_t MB = 1024 * 1024;
  f16*   Qh     = (f16*)(ws);                    // 8 MiB  [h][n][d]
  f16*   Kh     = (f16*)(ws + 8 * MB);           // 8 MiB  [h][n][d]
  f16*   Vt     = (f16*)(ws + 16 * MB);          // 8 MiB  [h][d][n]
  f16*   opart  = (f16*)(ws + 24 * MB);          // 24 MiB [sp3][h][qb32][d128][n128]
  float* mlpart = (float*)(ws + 48 * MB);        // 0.75 MiB
  f16*   wpT    = (f16*)(ws + 49 * MB);                       // 0.25 MiB
  f16*   wqkvT  = (f16*)(ws + 49 * MB + 256 * 1024);          // 0.75 MiB
  float* bperm  = (float*)(ws + 50 * MB);                     // 12 KiB

  hipLaunchKernelGGL(conv_weights, dim3(2048), dim3(256), 0, stream,
                     w_proj, w_qkv, b_qkv, wpT, wqkvT, bperm);
  hipLaunchKernelGGL(qkv_gemm2, dim3(24, 32), dim3(256), 0, stream,
                     x, wqkvT, bperm, Qh, Kh, Vt);
  hipLaunchKernelGGL(flash_attn, dim3(768), dim3(256), 0, stream,
                     Qh, Kh, Vt, opart, mlpart);
  hipLaunchKernelGGL(proj_combine, dim3(256), dim3(256), 0, stream,
                     opart, mlpart, wpT, b_proj, out);
}